// Round 1
// baseline (40.362 us; speedup 1.0000x reference)
//
#include <hip/hip_runtime.h>

#define NX 512
#define NY 512
#define NZ 64
#define NCELL (NX * NY * NZ)          // 16,777,216
#define NG4   (NX * NY * (NZ / 4))   // 4,194,304 float4 groups
#define STRIDE_X (NY * NZ)           // 32768 floats
#define STRIDE_Y (NZ)                // 64 floats

typedef float f4 __attribute__((ext_vector_type(4)));

// Per-cell term (summed over lattice then doubled):
//   T(i) = mz(i)*mx(i-ex) - mx(i)*mz(i-ex) + mz(i)*my(i-ey) - my(i)*mz(i-ey)
// out = D * CELLSIZE2 * sum(T) / NCELL        (0.5 * 2 = 1)

__global__ __launch_bounds__(256) void dmi_partial(const float* __restrict__ x,
                                                   float* __restrict__ ws) {
    const float* mx = x;
    const float* my = x + NCELL;
    const float* mz = x + 2 * NCELL;

    float acc = 0.0f;
    int tid = blockIdx.x * blockDim.x + threadIdx.x;
    int nthreads = gridDim.x * blockDim.x;

    for (int g = tid; g < NG4; g += nthreads) {
        // g = ix*8192 + iy*16 + iz4
        int iz4 = g & 15;
        int iy  = (g >> 4) & 511;
        int ix  = g >> 13;
        int off = (ix << 15) + (iy << 6) + (iz4 << 2);  // in floats

        f4 ax = *(const f4*)(mx + off);
        f4 ay = *(const f4*)(my + off);
        f4 az = *(const f4*)(mz + off);

        f4 t = (f4)(0.0f);
        if (ix > 0) {
            f4 bx = *(const f4*)(mx + off - STRIDE_X);
            f4 bz = *(const f4*)(mz + off - STRIDE_X);
            t += az * bx - ax * bz;
        }
        if (iy > 0) {
            f4 by = *(const f4*)(my + off - STRIDE_Y);
            f4 bz = *(const f4*)(mz + off - STRIDE_Y);
            t += az * by - ay * bz;
        }
        acc += t[0] + t[1] + t[2] + t[3];
    }

    // wave64 reduce
    for (int o = 32; o > 0; o >>= 1) acc += __shfl_down(acc, o);

    __shared__ float sacc[4];
    int lane = threadIdx.x & 63;
    int wid  = threadIdx.x >> 6;
    if (lane == 0) sacc[wid] = acc;
    __syncthreads();
    if (threadIdx.x == 0)
        ws[blockIdx.x] = sacc[0] + sacc[1] + sacc[2] + sacc[3];
}

__global__ __launch_bounds__(256) void dmi_final(const float* __restrict__ ws,
                                                 const float* __restrict__ D,
                                                 float* __restrict__ out,
                                                 int nblocks) {
    double acc = 0.0;
    for (int i = threadIdx.x; i < nblocks; i += 256) acc += (double)ws[i];

    for (int o = 32; o > 0; o >>= 1) acc += __shfl_down(acc, o);

    __shared__ double sacc[4];
    int lane = threadIdx.x & 63;
    int wid  = threadIdx.x >> 6;
    if (lane == 0) sacc[wid] = acc;
    __syncthreads();
    if (threadIdx.x == 0) {
        double total = sacc[0] + sacc[1] + sacc[2] + sacc[3];
        double scale = (double)D[0] * 4e-18 / (double)NCELL;  // CELLSIZE2 = (2e-9)^2
        out[0] = (float)(total * scale);
    }
}

extern "C" void kernel_launch(void* const* d_in, const int* in_sizes, int n_in,
                              void* d_out, int out_size, void* d_ws, size_t ws_size,
                              hipStream_t stream) {
    const float* x = (const float*)d_in[0];
    // d_in[1] = geo (unused by forward)
    const float* D = (const float*)d_in[2];
    float* out = (float*)d_out;
    float* ws  = (float*)d_ws;

    int nblocks = 2048;
    size_t avail = ws_size / sizeof(float);
    if ((size_t)nblocks > avail) nblocks = (int)(avail > 0 ? avail : 1);

    dmi_partial<<<nblocks, 256, 0, stream>>>(x, ws);
    dmi_final<<<1, 256, 0, stream>>>(ws, D, out, nblocks);
}